// Round 1
// baseline (364.147 us; speedup 1.0000x reference)
//
#include <hip/hip_runtime.h>
#include <math.h>

// PANLoss: dice(regions) + 0.5*dice(kernels) + 0.25*(agg + dis)
//
// R9 = LDS-histogram rewrite. R8's VGPR_Count=28 proved the 24-float
// accumulator arrays (St_/Sk_/Ss_ + counts) forced the compiler to
// serialize the 10 NT loads (40 VGPRs of destinations can't fit in 28)
// AND cost ~256 VALU ops of compare-tree + 180 ds_bpermute of reduction
// tail per thread. Replace both with ds_add_f32 atomics into one
// per-block LDS histogram whose layout matches the ws slot map; the
// background label (0) lands in the already-unused slots 0/9/18/27/36.
// Memory side (grid, 10 NT float4 loads per thread) is IDENTICAL to R8
// so the memory-system-ceiling hypothesis is cleanly isolated.
//
// ws per batch (NACC=51 floats):
//   [0..8] ct  [9..17] ck  [18..26] St  [27..35] Sk  [36..44] Ss
//   (slot 0 of each group = background, ignored by finalize)
//   [45..47] regions pg/pp/gg   [48..50] kernels pg/pp/gg

#define NSEG 9
#define NACC 51
#define NBATCH 16
#define EPSF 1e-5f
#define BPB 400  // blocks per batch: 102400 float4 / 256 = 400 exact

typedef float  vfloat4 __attribute__((ext_vector_type(4)));
typedef int    vint4   __attribute__((ext_vector_type(4)));

__device__ __forceinline__ float wave_reduce_sum(float v) {
#pragma unroll
    for (int off = 32; off > 0; off >>= 1)
        v += __shfl_down(v, off, 64);
    return v;
}

__device__ __forceinline__ float sigm(float x) {
    return 1.0f / (1.0f + __expf(-x));
}

__device__ __forceinline__ vfloat4 nt_load4(const float* p) {
    return __builtin_nontemporal_load((const vfloat4*)p);
}
__device__ __forceinline__ vint4 nt_load4i(const int* p) {
    return __builtin_nontemporal_load((const vint4*)p);
}

__global__ __launch_bounds__(256) void pan_main(
    const float* __restrict__ pred_r, const float* __restrict__ gt_r,
    const float* __restrict__ pred_k, const float* __restrict__ gt_k,
    const float* __restrict__ sim,
    const int* __restrict__ tlab, const int* __restrict__ klab,
    float* __restrict__ ws, int npix)
{
    __shared__ float h[NACC];
    const int tid = threadIdx.x;
    if (tid < NACC) h[tid] = 0.0f;
    __syncthreads();

    const int b = blockIdx.y;
    const int i = blockIdx.x * 256 + tid;
    const long long e = (long long)i * 4;  // element offset of this float4
    const long long base = (long long)b * npix;
    const long long sbase = (long long)b * 4 * npix;

    // ---- issue all 10 independent NT loads back-to-back ----
    // (now actually possible: no accumulator arrays competing for VGPRs)
    const vfloat4 pr = nt_load4(pred_r + base + e);
    const vfloat4 gr = nt_load4(gt_r + base + e);
    const vfloat4 pk = nt_load4(pred_k + base + e);
    const vfloat4 gk = nt_load4(gt_k + base + e);
    const vfloat4 c0 = nt_load4(sim + sbase + e);
    const vfloat4 c1 = nt_load4(sim + sbase + npix + e);
    const vfloat4 c2 = nt_load4(sim + sbase + 2LL * npix + e);
    const vfloat4 c3 = nt_load4(sim + sbase + 3LL * npix + e);
    const vint4 tl = nt_load4i(tlab + base + e);
    const vint4 kl = nt_load4i(klab + base + e);

    // ---- dice sums (g in {0,1} so g*g == g) ----
    float rpg, rpp, rgg, kpg, kpp, kgg;
    {
        float p;
        p = sigm(pr.x); rpg  = p * gr.x; rpp  = p * p; rgg  = gr.x;
        p = sigm(pr.y); rpg += p * gr.y; rpp += p * p; rgg += gr.y;
        p = sigm(pr.z); rpg += p * gr.z; rpp += p * p; rgg += gr.z;
        p = sigm(pr.w); rpg += p * gr.w; rpp += p * p; rgg += gr.w;
        p = sigm(pk.x); kpg  = p * gk.x; kpp  = p * p; kgg  = gk.x;
        p = sigm(pk.y); kpg += p * gk.y; kpp += p * p; kgg += gk.y;
        p = sigm(pk.z); kpg += p * gk.z; kpp += p * p; kgg += gk.z;
        p = sigm(pk.w); kpg += p * gk.w; kpp += p * p; kgg += gk.w;
    }

    // ---- per-pixel squared feature norm ----
    const float s2x = c0.x * c0.x + c1.x * c1.x + c2.x * c2.x + c3.x * c3.x;
    const float s2y = c0.y * c0.y + c1.y * c1.y + c2.y * c2.y + c3.y * c3.y;
    const float s2z = c0.z * c0.z + c1.z * c1.z + c2.z * c2.z + c3.z * c3.z;
    const float s2w = c0.w * c0.w + c1.w * c1.w + c2.w * c2.w + c3.w * c3.w;

    // ---- label histograms: 5 ds_add_f32 per component, no compare tree ----
    // ct at [0+tl], ck at [9+kl], St at [18+tl], Sk at [27+kl], Ss at [36+tl]
#define DO_COMP(TL, KL, S2)                                   \
    {                                                         \
        atomicAdd(&h[(TL)], 1.0f);                            \
        atomicAdd(&h[9 + (KL)], 1.0f);                        \
        atomicAdd(&h[18 + (TL)], (S2));                       \
        atomicAdd(&h[27 + (KL)], (S2));                       \
        if ((TL) == (KL)) atomicAdd(&h[36 + (TL)], (S2));     \
    }
    DO_COMP(tl.x, kl.x, s2x);
    DO_COMP(tl.y, kl.y, s2y);
    DO_COMP(tl.z, kl.z, s2z);
    DO_COMP(tl.w, kl.w, s2w);
#undef DO_COMP

    // ---- dice: wave shuffle reduce (6 quantities), lane0 -> LDS atomic ----
    rpg = wave_reduce_sum(rpg);
    rpp = wave_reduce_sum(rpp);
    rgg = wave_reduce_sum(rgg);
    kpg = wave_reduce_sum(kpg);
    kpp = wave_reduce_sum(kpp);
    kgg = wave_reduce_sum(kgg);
    if ((tid & 63) == 0) {
        atomicAdd(&h[45], rpg);
        atomicAdd(&h[46], rpp);
        atomicAdd(&h[47], rgg);
        atomicAdd(&h[48], kpg);
        atomicAdd(&h[49], kpp);
        atomicAdd(&h[50], kgg);
    }

    __syncthreads();
    if (tid < NACC) atomicAdd(&ws[b * NACC + tid], h[tid]);
}

__global__ __launch_bounds__(64) void pan_finalize(
    const float* __restrict__ ws, float* __restrict__ out)
{
    const int b = threadIdx.x;
    float dice_r = 0.0f, dice_k = 0.0f, lagg = 0.0f, ldis = 0.0f;

    if (b < NBATCH) {
        const float* w = ws + b * NACC;
        {
            float pg = w[45], pp = w[46], gg = w[47];
            dice_r = 1.0f - (2.0f * pg + EPSF) / ((pp + EPSF) + (gg + EPSF));
            pg = w[48]; pp = w[49]; gg = w[50];
            dice_k = 1.0f - (2.0f * pg + EPSF) / ((pp + EPSF) + (gg + EPSF));
        }
        float a[8];
#pragma unroll
        for (int i = 1; i < NSEG; ++i) {
            float ct = w[i], ck = w[NSEG + i];
            float St = w[2 * NSEG + i], Sk = w[3 * NSEG + i], Ss = w[4 * NSEG + i];
            float inv = 1.0f / (ck + 1.0f);
            float omi = 1.0f - inv;
            float n2 = omi * omi * Ss + (St - Ss) + inv * inv * (Sk - Ss);
            float nrm = sqrtf(n2);
            float d = nrm - 0.5f;  // SIGMA_AGG (no clamp — matches reference)
            lagg += logf(d * d + 1.0f) / (ct + 1.0f);
            float ckd = ck + 0.001f;
            a[i - 1] = Sk / (ckd * ckd);
        }
#pragma unroll
        for (int i = 0; i < 8; ++i) {
#pragma unroll
            for (int j = i + 1; j < 8; ++j) {
                float pair = 3.0f - sqrtf(a[i] + a[j]);  // SIGMA_DIS
                ldis += logf(pair * pair + 1.0f);
            }
        }
        ldis *= (1.0f / 56.0f);  // K_MAX*(K_MAX-1)
    }

    dice_r = wave_reduce_sum(dice_r);
    dice_k = wave_reduce_sum(dice_k);
    lagg = wave_reduce_sum(lagg);
    ldis = wave_reduce_sum(ldis);

    if (threadIdx.x == 0) {
        float loss = dice_r + 0.5f * dice_k + 0.25f * (lagg + ldis);
        out[0] = loss;
        out[1] = dice_r;
        out[2] = dice_k;
        out[3] = lagg;
        out[4] = ldis;
    }
}

extern "C" void kernel_launch(void* const* d_in, const int* in_sizes, int n_in,
                              void* d_out, int out_size, void* d_ws, size_t ws_size,
                              hipStream_t stream) {
    const float* pred_r = (const float*)d_in[0];
    const float* gt_r   = (const float*)d_in[1];
    const float* pred_k = (const float*)d_in[2];
    const float* gt_k   = (const float*)d_in[3];
    const float* sim    = (const float*)d_in[4];
    const int*   tlab   = (const int*)d_in[5];
    const int*   klab   = (const int*)d_in[6];
    float* out = (float*)d_out;
    float* ws  = (float*)d_ws;

    const int npix = in_sizes[0] / NBATCH;  // 640*640 = 409600

    (void)hipMemsetAsync(ws, 0, NBATCH * NACC * sizeof(float), stream);

    dim3 grid(BPB, NBATCH);
    pan_main<<<grid, 256, 0, stream>>>(pred_r, gt_r, pred_k, gt_k, sim,
                                       tlab, klab, ws, npix);
    pan_finalize<<<1, 64, 0, stream>>>(ws, out);
}

// Round 2
// 251.564 us; speedup vs baseline: 1.4475x; 1.4475x over previous
//
#include <hip/hip_runtime.h>
#include <math.h>

// PANLoss: dice(regions) + 0.5*dice(kernels) + 0.25*(agg + dis)
//
// R10 = R8's ballot structure + G=5 amortization of the reduction tail.
//
// R9 post-mortem: LDS fp atomics with 9-way same-address contention
// bottlenecked the single per-CU DS pipe (dur 165us, all other pipes
// idle). Reverted to ballot/popcount gather (R8, 81.8us proven).
//
// R8 residual analysis: the 30-quantity x 6-shuffle reduction tail
// (~360 DS+VALU ops) is a FIXED per-thread cost that R8 paid every 4
// pixels. R10 processes G=5 float4s (20 pixels) per thread -> tail
// amortized 5x; compare tree and loads stay proportional. Grid
// 80x16=1280 blocks = exactly 5 blocks/CU. '#pragma unroll 1' on the
// G-loop bounds VGPR pressure (10 loads in flight per wave).
//
// ws per batch (NACC=51 floats, slots 0,9,18,27,36 unused/zero):
//   [1..8] ct  [10..17] ck  [19..26] St  [28..35] Sk  [37..44] Ss
//   [45..47] regions pg/pp/gg   [48..50] kernels pg/pp/gg

#define NSEG 9
#define NACC 51
#define NBATCH 16
#define EPSF 1e-5f
#define G 5          // float4 groups per thread
#define BPB 80       // blocks per batch: 102400 float4 / (256*G) = 80 exact

typedef float  vfloat4 __attribute__((ext_vector_type(4)));
typedef int    vint4   __attribute__((ext_vector_type(4)));

__device__ __forceinline__ float wave_reduce_sum(float v) {
#pragma unroll
    for (int off = 32; off > 0; off >>= 1)
        v += __shfl_down(v, off, 64);
    return v;
}

__device__ __forceinline__ float sigm(float x) {
    return 1.0f / (1.0f + __expf(-x));
}

__device__ __forceinline__ vfloat4 nt_load4(const float* p) {
    return __builtin_nontemporal_load((const vfloat4*)p);
}
__device__ __forceinline__ vint4 nt_load4i(const int* p) {
    return __builtin_nontemporal_load((const vint4*)p);
}

__global__ __launch_bounds__(256) void pan_main(
    const float* __restrict__ pred_r, const float* __restrict__ gt_r,
    const float* __restrict__ pred_k, const float* __restrict__ gt_k,
    const float* __restrict__ sim,
    const int* __restrict__ tlab, const int* __restrict__ klab,
    float* __restrict__ ws, int npix)
{
    const int tid = threadIdx.x;
    const int b = blockIdx.y;
    const long long base = (long long)b * npix;
    const long long sbase = (long long)b * 4 * npix;
    const int i0 = blockIdx.x * (256 * G) + tid;  // float4 index of group 0

    float St_[8], Sk_[8], Ss_[8];
    unsigned ct_[8], ck_[8];
#pragma unroll
    for (int s = 0; s < 8; ++s) {
        St_[s] = 0.0f; Sk_[s] = 0.0f; Ss_[s] = 0.0f;
        ct_[s] = 0u; ck_[s] = 0u;
    }
    float rpg = 0.0f, rpp = 0.0f, rgg = 0.0f;
    float kpg = 0.0f, kpp = 0.0f, kgg = 0.0f;

#pragma unroll 1
    for (int g = 0; g < G; ++g) {
        const long long e = (long long)(i0 + g * 256) * 4;  // element offset

        // ---- 10 independent NT loads ----
        const vfloat4 pr = nt_load4(pred_r + base + e);
        const vfloat4 gr = nt_load4(gt_r + base + e);
        const vfloat4 pk = nt_load4(pred_k + base + e);
        const vfloat4 gk = nt_load4(gt_k + base + e);
        const vfloat4 c0 = nt_load4(sim + sbase + e);
        const vfloat4 c1 = nt_load4(sim + sbase + npix + e);
        const vfloat4 c2 = nt_load4(sim + sbase + 2LL * npix + e);
        const vfloat4 c3 = nt_load4(sim + sbase + 3LL * npix + e);
        const vint4 tl = nt_load4i(tlab + base + e);
        const vint4 kl = nt_load4i(klab + base + e);

        // ---- dice sums (g in {0,1} so g*g == g) ----
        {
            float p;
            p = sigm(pr.x); rpg += p * gr.x; rpp += p * p; rgg += gr.x;
            p = sigm(pr.y); rpg += p * gr.y; rpp += p * p; rgg += gr.y;
            p = sigm(pr.z); rpg += p * gr.z; rpp += p * p; rgg += gr.z;
            p = sigm(pr.w); rpg += p * gr.w; rpp += p * p; rgg += gr.w;
            p = sigm(pk.x); kpg += p * gk.x; kpp += p * p; kgg += gk.x;
            p = sigm(pk.y); kpg += p * gk.y; kpp += p * p; kgg += gk.y;
            p = sigm(pk.z); kpg += p * gk.z; kpp += p * p; kgg += gk.z;
            p = sigm(pk.w); kpg += p * gk.w; kpp += p * p; kgg += gk.w;
        }

        const float s2x = c0.x * c0.x + c1.x * c1.x + c2.x * c2.x + c3.x * c3.x;
        const float s2y = c0.y * c0.y + c1.y * c1.y + c2.y * c2.y + c3.y * c3.y;
        const float s2z = c0.z * c0.z + c1.z * c1.z + c2.z * c2.z + c3.z * c3.z;
        const float s2w = c0.w * c0.w + c1.w * c1.w + c2.w * c2.w + c3.w * c3.w;

#define DO_COMP(TL, KL, S2)                                      \
        {                                                        \
            bool tt = ((TL) == s);                               \
            bool kk = ((KL) == s);                               \
            ct_[s - 1] += (unsigned)__popcll(__ballot(tt));      \
            ck_[s - 1] += (unsigned)__popcll(__ballot(kk));      \
            St_[s - 1] += tt ? (S2) : 0.0f;                      \
            Sk_[s - 1] += kk ? (S2) : 0.0f;                      \
            Ss_[s - 1] += (tt && kk) ? (S2) : 0.0f;              \
        }

#pragma unroll
        for (int s = 1; s <= 8; ++s) {
            DO_COMP(tl.x, kl.x, s2x);
            DO_COMP(tl.y, kl.y, s2y);
            DO_COMP(tl.z, kl.z, s2z);
            DO_COMP(tl.w, kl.w, s2w);
        }
#undef DO_COMP
    }

    // ---- block reduction: wave shuffle -> LDS -> one atomicAdd per qty ----
    __shared__ float red[4][NACC];
    const int lane = tid & 63;
    const int wv = tid >> 6;

#pragma unroll
    for (int s = 0; s < 8; ++s) {
        float v;
        v = wave_reduce_sum(St_[s]); if (lane == 0) red[wv][19 + s] = v;
        v = wave_reduce_sum(Sk_[s]); if (lane == 0) red[wv][28 + s] = v;
        v = wave_reduce_sum(Ss_[s]); if (lane == 0) red[wv][37 + s] = v;
    }
    {
        float v;
        v = wave_reduce_sum(rpg); if (lane == 0) red[wv][45] = v;
        v = wave_reduce_sum(rpp); if (lane == 0) red[wv][46] = v;
        v = wave_reduce_sum(rgg); if (lane == 0) red[wv][47] = v;
        v = wave_reduce_sum(kpg); if (lane == 0) red[wv][48] = v;
        v = wave_reduce_sum(kpp); if (lane == 0) red[wv][49] = v;
        v = wave_reduce_sum(kgg); if (lane == 0) red[wv][50] = v;
    }
    if (lane == 0) {
        // ballot counts are wave-uniform
#pragma unroll
        for (int s = 0; s < 8; ++s) {
            red[wv][1 + s] = (float)ct_[s];
            red[wv][10 + s] = (float)ck_[s];
        }
        red[wv][0] = 0.0f; red[wv][9] = 0.0f; red[wv][18] = 0.0f;
        red[wv][27] = 0.0f; red[wv][36] = 0.0f;
    }
    __syncthreads();
    if (tid < NACC) {
        float s = red[0][tid] + red[1][tid] + red[2][tid] + red[3][tid];
        atomicAdd(&ws[b * NACC + tid], s);
    }
}

__global__ __launch_bounds__(64) void pan_finalize(
    const float* __restrict__ ws, float* __restrict__ out)
{
    const int b = threadIdx.x;
    float dice_r = 0.0f, dice_k = 0.0f, lagg = 0.0f, ldis = 0.0f;

    if (b < NBATCH) {
        const float* w = ws + b * NACC;
        {
            float pg = w[45], pp = w[46], gg = w[47];
            dice_r = 1.0f - (2.0f * pg + EPSF) / ((pp + EPSF) + (gg + EPSF));
            pg = w[48]; pp = w[49]; gg = w[50];
            dice_k = 1.0f - (2.0f * pg + EPSF) / ((pp + EPSF) + (gg + EPSF));
        }
        float a[8];
#pragma unroll
        for (int i = 1; i < NSEG; ++i) {
            float ct = w[i], ck = w[NSEG + i];
            float St = w[2 * NSEG + i], Sk = w[3 * NSEG + i], Ss = w[4 * NSEG + i];
            float inv = 1.0f / (ck + 1.0f);
            float omi = 1.0f - inv;
            float n2 = omi * omi * Ss + (St - Ss) + inv * inv * (Sk - Ss);
            float nrm = sqrtf(n2);
            float d = nrm - 0.5f;  // SIGMA_AGG (no clamp — matches reference)
            lagg += logf(d * d + 1.0f) / (ct + 1.0f);
            float ckd = ck + 0.001f;
            a[i - 1] = Sk / (ckd * ckd);
        }
#pragma unroll
        for (int i = 0; i < 8; ++i) {
#pragma unroll
            for (int j = i + 1; j < 8; ++j) {
                float pair = 3.0f - sqrtf(a[i] + a[j]);  // SIGMA_DIS
                ldis += logf(pair * pair + 1.0f);
            }
        }
        ldis *= (1.0f / 56.0f);  // K_MAX*(K_MAX-1)
    }

    dice_r = wave_reduce_sum(dice_r);
    dice_k = wave_reduce_sum(dice_k);
    lagg = wave_reduce_sum(lagg);
    ldis = wave_reduce_sum(ldis);

    if (threadIdx.x == 0) {
        float loss = dice_r + 0.5f * dice_k + 0.25f * (lagg + ldis);
        out[0] = loss;
        out[1] = dice_r;
        out[2] = dice_k;
        out[3] = lagg;
        out[4] = ldis;
    }
}

extern "C" void kernel_launch(void* const* d_in, const int* in_sizes, int n_in,
                              void* d_out, int out_size, void* d_ws, size_t ws_size,
                              hipStream_t stream) {
    const float* pred_r = (const float*)d_in[0];
    const float* gt_r   = (const float*)d_in[1];
    const float* pred_k = (const float*)d_in[2];
    const float* gt_k   = (const float*)d_in[3];
    const float* sim    = (const float*)d_in[4];
    const int*   tlab   = (const int*)d_in[5];
    const int*   klab   = (const int*)d_in[6];
    float* out = (float*)d_out;
    float* ws  = (float*)d_ws;

    const int npix = in_sizes[0] / NBATCH;  // 640*640 = 409600

    (void)hipMemsetAsync(ws, 0, NBATCH * NACC * sizeof(float), stream);

    dim3 grid(BPB, NBATCH);
    pan_main<<<grid, 256, 0, stream>>>(pred_r, gt_r, pred_k, gt_k, sim,
                                       tlab, klab, ws, npix);
    pan_finalize<<<1, 64, 0, stream>>>(ws, out);
}